// Round 3
// baseline (523.644 us; speedup 1.0000x reference)
//
#include <hip/hip_runtime.h>
#include <hip/hip_bf16.h>

// ---------------------------------------------------------------------------
// Round 2: bf16-MFMA for the GEMM-heavy stages (k_l0, 3x3 convs); fp32 for
// conv1/attn/fc/final. Padded NHWC maps + zeroed borders as before.
// Pipeline: k_zero -> k_w0t + k_wtb x4 -> k_conv1 -> k_conv3x3m x4 ->
//           k_attn -> k_l0m (fused gather+attn GEMM, K=9408 MFMA + 2 fp32)
//           -> k_fc x3 -> k_final.
// MFMA layout (guide §3, m89-verified): C/D col=lane&15,row=(lane>>4)*4+reg;
// A/B lane holds 8 k-contiguous bf16 at k=(lane>>4)*8.
// ---------------------------------------------------------------------------

constexpr int BB = 2, QQ = 4096, DIMC = 192, RAW = 49;
constexpr int ENC = 64, P1 = 66, P3 = 70;

typedef __attribute__((ext_vector_type(8))) short bf16x8;
typedef __attribute__((ext_vector_type(4))) float f32x4;

__device__ inline short f2bf(float f) {
  __hip_bfloat16 h = __float2bfloat16(f);
  return __builtin_bit_cast(short, h);
}

// ws offsets in float units
constexpr long long N_F1 = (long long)BB * P1 * P1 * ENC;    // 557568
constexpr long long N_FT = (long long)BB * P1 * P1 * DIMC;   // 1672704
constexpr long long N_FK = (long long)BB * P3 * P3 * DIMC;   // 1881600
constexpr long long F_F1 = 0;
constexpr long long F_FEAT = F_F1 + N_F1;
constexpr long long F_FQ = F_FEAT + N_FT;
constexpr long long F_FK = F_FQ + N_FT;
constexpr long long F_FV = F_FK + N_FT + (N_FK - N_FT);      // = F_FK + N_FK
constexpr long long F_ATTN = F_FV + N_FK;                    // zero region ends here
constexpr long long F_HA = F_ATTN + (long long)BB * QQ * RAW * 8;
constexpr long long F_HB = F_HA + 8192LL * 256;
constexpr long long F_W0T = F_HB + 8192LL * 256;             // shorts region (float-sized units)
constexpr long long F_WTCHB = F_W0T + (256LL * 9408 * 2 + 3) / 4;
constexpr long long F_WTQB = F_WTCHB + (192LL * 576 * 2 + 3) / 4;
constexpr long long F_WTKB = F_WTQB + (192LL * 1728 * 2 + 3) / 4;
constexpr long long F_WTVB = F_WTKB + (192LL * 1728 * 2 + 3) / 4;
constexpr long long ZERO_N4 = F_ATTN / 4;

__global__ __launch_bounds__(256) void k_zero(float4* p, int n4) {
  int i = blockIdx.x * 256 + threadIdx.x;
  float4 z = make_float4(0.f, 0.f, 0.f, 0.f);
  for (; i < n4; i += gridDim.x * 256) p[i] = z;
}

// w0 [9408+2][256] fp32 -> w0t [256][9408] bf16 (LDS tile transpose)
__global__ __launch_bounds__(256) void k_w0t(const float* __restrict__ w0,
                                             short* __restrict__ w0t) {
  __shared__ short sh[64][72];
  int k0 = blockIdx.x * 64, n0 = blockIdx.y * 64;
  int t = threadIdx.x;
  #pragma unroll
  for (int i = 0; i < 16; i++) {
    int idx = t + i * 256;
    int r = idx >> 6, cc = idx & 63;  // r: k-offset, cc: n-offset
    sh[cc][r] = f2bf(w0[(long long)(k0 + r) * 256 + n0 + cc]);
  }
  __syncthreads();
  #pragma unroll
  for (int i = 0; i < 16; i++) {
    int idx = t + i * 256;
    int n = idx >> 6, k = idx & 63;
    w0t[(long long)(n0 + n) * 9408 + k0 + k] = sh[n][k];
  }
}

// conv w [CO][CI][3][3] fp32 -> wtb [CO][9*CI] bf16 with k = tap*CI + ci
__global__ __launch_bounds__(256) void k_wtb(const float* __restrict__ w,
                                             short* __restrict__ wtb, int CI, int CO) {
  int g = blockIdx.x * 256 + threadIdx.x;
  if (g >= CO * CI * 9) return;
  int co = g / (CI * 9);
  int r = g - co * CI * 9;
  int ci = r / 9, t = r - ci * 9;
  wtb[(long long)co * (9 * CI) + t * CI + ci] = f2bf(w[g]);
}

// inp [B][3][64][64] -> f1p [B][66][66][64] interior (fp32, tiny)
__global__ __launch_bounds__(256) void k_conv1(const float* __restrict__ inp,
                                               const float* __restrict__ ew,
                                               const float* __restrict__ eb,
                                               float* __restrict__ f1p) {
  int g = blockIdx.x * 256 + threadIdx.x;
  int co = g & 63, x = (g >> 6) & 63, y = (g >> 12) & 63, b = g >> 18;
  float acc = eb[co];
  #pragma unroll
  for (int ci = 0; ci < 3; ci++)
    #pragma unroll
    for (int ky = 0; ky < 3; ky++) {
      int yy = y + ky - 1;
      if (yy < 0 || yy > 63) continue;
      #pragma unroll
      for (int kx = 0; kx < 3; kx++) {
        int xx = x + kx - 1;
        if (xx < 0 || xx > 63) continue;
        acc += inp[((b * 3 + ci) * 64 + yy) * 64 + xx] * ew[((co * 3 + ci) * 3 + ky) * 3 + kx];
      }
    }
  f1p[((b * P1 + y + 1) * P1 + (x + 1)) * ENC + co] = acc;
}

// MFMA 3x3 conv: in [B][66][66][CIN] fp32 padded; wtb [CO][9*CIN] bf16.
// Block: 64 x-pixels (one y row) x 64 out-channels; 4 waves 2x2; acc 2x2 frags.
template <int CIN>
__global__ __launch_bounds__(256) void k_conv3x3m(const float* __restrict__ in,
                                                  const short* __restrict__ wtb,
                                                  const float* __restrict__ bias,
                                                  float* __restrict__ out, int pitchO,
                                                  int padO, int COUT) {
  constexpr int NCH = CIN / 64;  // k-chunks per tap
  int nb = blockIdx.x;
  int by = blockIdx.y;
  int b = by >> 6, y = by & 63;
  int t = threadIdx.x;
  int lane = t & 63, w = t >> 6, wr = w >> 1, wc = w & 1;
  __shared__ __align__(16) short As[64][72];
  __shared__ __align__(16) short Bs[64][72];
  f32x4 acc[2][2];
  #pragma unroll
  for (int i = 0; i < 2; i++)
    #pragma unroll
    for (int j = 0; j < 2; j++) acc[i][j] = (f32x4){0.f, 0.f, 0.f, 0.f};
  int arow = t >> 2, kq = t & 3;
  int nbase = nb * 64;
  const long long K9 = 9LL * CIN;
  for (int c = 0; c < 9 * NCH; c++) {
    int t9 = c / NCH, sub = c - t9 * NCH;
    int dy = t9 / 3 - 1, dx = t9 % 3 - 1;
    __syncthreads();
    {
      const float* src = in + (((long long)b * P1 + y + dy + 1) * P1 + (arow + dx + 1)) * CIN +
                         sub * 64 + kq * 16;
      bf16x8 pk0, pk1;
      #pragma unroll
      for (int j = 0; j < 2; j++) {
        float4 v = *(const float4*)(src + j * 4);
        pk0[j * 4 + 0] = f2bf(v.x);
        pk0[j * 4 + 1] = f2bf(v.y);
        pk0[j * 4 + 2] = f2bf(v.z);
        pk0[j * 4 + 3] = f2bf(v.w);
      }
      #pragma unroll
      for (int j = 0; j < 2; j++) {
        float4 v = *(const float4*)(src + 8 + j * 4);
        pk1[j * 4 + 0] = f2bf(v.x);
        pk1[j * 4 + 1] = f2bf(v.y);
        pk1[j * 4 + 2] = f2bf(v.z);
        pk1[j * 4 + 3] = f2bf(v.w);
      }
      *(bf16x8*)&As[arow][kq * 16] = pk0;
      *(bf16x8*)&As[arow][kq * 16 + 8] = pk1;
      const short* wp = wtb + (long long)(nbase + arow) * K9 + c * 64 + kq * 16;
      *(bf16x8*)&Bs[arow][kq * 16] = *(const bf16x8*)wp;
      *(bf16x8*)&Bs[arow][kq * 16 + 8] = *(const bf16x8*)(wp + 8);
    }
    __syncthreads();
    #pragma unroll
    for (int kk = 0; kk < 2; kk++) {
      bf16x8 a0 = *(const bf16x8*)&As[wr * 32 + (lane & 15)][kk * 32 + (lane >> 4) * 8];
      bf16x8 a1 = *(const bf16x8*)&As[wr * 32 + 16 + (lane & 15)][kk * 32 + (lane >> 4) * 8];
      bf16x8 b0 = *(const bf16x8*)&Bs[wc * 32 + (lane & 15)][kk * 32 + (lane >> 4) * 8];
      bf16x8 b1 = *(const bf16x8*)&Bs[wc * 32 + 16 + (lane & 15)][kk * 32 + (lane >> 4) * 8];
      acc[0][0] = __builtin_amdgcn_mfma_f32_16x16x32_bf16(a0, b0, acc[0][0], 0, 0, 0);
      acc[0][1] = __builtin_amdgcn_mfma_f32_16x16x32_bf16(a0, b1, acc[0][1], 0, 0, 0);
      acc[1][0] = __builtin_amdgcn_mfma_f32_16x16x32_bf16(a1, b0, acc[1][0], 0, 0, 0);
      acc[1][1] = __builtin_amdgcn_mfma_f32_16x16x32_bf16(a1, b1, acc[1][1], 0, 0, 0);
    }
  }
  int col0 = nbase + wc * 32 + (lane & 15);
  int row0 = wr * 32 + ((lane >> 4) << 2);
  #pragma unroll
  for (int nf = 0; nf < 2; nf++) {
    int co = col0 + nf * 16;
    float bv = bias[co];
    #pragma unroll
    for (int mf = 0; mf < 2; mf++)
      #pragma unroll
      for (int i = 0; i < 4; i++) {
        int x = row0 + mf * 16 + i;
        out[(((long long)b * pitchO + y + padO) * pitchO + (x + padO)) * COUT + co] =
            acc[mf][nf][i] + bv;
      }
  }
}

// per-query attention probs: attnO[bq][49][8] (fp32)
__global__ __launch_bounds__(64) void k_attn(const float* __restrict__ sc,
                                             const float* __restrict__ fq,
                                             const float* __restrict__ fk,
                                             float* __restrict__ attnO) {
  int bq = blockIdx.x;
  int b = bq >> 12;
  int lane = threadIdx.x;
  float cy = sc[bq * 2 + 0], cx = sc[bq * 2 + 1];
  float py = (cy + 1.f) * 32.f - 0.5f, px = (cx + 1.f) * 32.f - 0.5f;
  float fy = floorf(py), fx = floorf(px);
  float wy = py - fy, wx = px - fx;
  int iy = (int)fy, ix = (int)fx;
  __shared__ __align__(16) float qv[192];
  {
    const float* base = fq + (((long long)b * P1 + iy + 1) * P1 + (ix + 1)) * DIMC;
    #pragma unroll
    for (int u = 0; u < 3; u++) {
      int c = lane * 3 + u;
      float v00 = base[c], v01 = base[DIMC + c];
      float v10 = base[P1 * DIMC + c], v11 = base[P1 * DIMC + DIMC + c];
      qv[c] = (1.f - wy) * ((1.f - wx) * v00 + wx * v01) +
              wy * ((1.f - wx) * v10 + wx * v11);
    }
  }
  __syncthreads();
  int icy = min(max((int)floorf(py + 0.5f), 0), 63);
  int icx = min(max((int)floorf(px + 0.5f), 0), 63);
  float l[8];
  #pragma unroll
  for (int h = 0; h < 8; h++) l[h] = -1e30f;
  if (lane < 49) {
    int dy = lane / 7 - 3, dx = lane % 7 - 3;
    const float4* kb =
        (const float4*)(fk + (((long long)b * P3 + icy + dy + 3) * P3 + (icx + dx + 3)) * DIMC);
    #pragma unroll
    for (int h = 0; h < 8; h++) l[h] = 0.f;
    #pragma unroll
    for (int c4 = 0; c4 < 48; c4++) {
      float4 k4 = kb[c4];
      float4 q4 = *(const float4*)&qv[c4 * 4];
      l[c4 / 6] += q4.x * k4.x + q4.y * k4.y + q4.z * k4.z + q4.w * k4.w;
    }
    const float s = 0.20412414523193154f;  // 1/sqrt(24)
    #pragma unroll
    for (int h = 0; h < 8; h++) l[h] *= s;
  }
  float a[8];
  #pragma unroll
  for (int h = 0; h < 8; h++) {
    float mx = l[h];
    #pragma unroll
    for (int s = 1; s < 64; s <<= 1) mx = fmaxf(mx, __shfl_xor(mx, s));
    float e = (lane < 49) ? expf(l[h] - mx) : 0.f;
    float sm = e;
    #pragma unroll
    for (int s = 1; s < 64; s <<= 1) sm += __shfl_xor(sm, s);
    a[h] = e / sm;
  }
  if (lane < 49) {
    float* op = attnO + ((long long)bq * 49 + lane) * 8;
    *(float4*)op = make_float4(a[0], a[1], a[2], a[3]);
    *(float4*)(op + 4) = make_float4(a[4], a[5], a[6], a[7]);
  }
}

// MFMA fused gather+attn-weight GEMM: h = relu(A[8192,9408] @ w0t^T + tail)
__global__ __launch_bounds__(256) void k_l0m(const float* __restrict__ sc,
                                             const float* __restrict__ cell,
                                             const float* __restrict__ fv,
                                             const float* __restrict__ attn,
                                             const short* __restrict__ w0t,
                                             const float* __restrict__ w0,
                                             const float* __restrict__ b0,
                                             float* __restrict__ hout) {
  int nb = blockIdx.x;  // 0..3
  int mb = blockIdx.y;  // 0..127
  int qbase = mb * 64;
  int b = qbase >> 12;
  int t = threadIdx.x;
  int lane = t & 63, w = t >> 6, wr = w >> 1, wc = w & 1;
  __shared__ __align__(16) short As[64][72];
  __shared__ __align__(16) short Bs[64][72];
  int arow = t >> 2, kq = t & 3;
  int q = qbase + arow;
  float cy = sc[q * 2 + 0], cx = sc[q * 2 + 1];
  float py = (cy + 1.f) * 32.f - 0.5f, px = (cx + 1.f) * 32.f - 0.5f;
  int icy = min(max((int)floorf(py + 0.5f), 0), 63);
  int icx = min(max((int)floorf(px + 0.5f), 0), 63);
  const float* fvb = fv + (((long long)b * P3 + icy + 3) * P3 + (icx + 3)) * DIMC;
  const float* ap = attn + (long long)q * 49 * 8;
  f32x4 acc[2][2];
  #pragma unroll
  for (int i = 0; i < 2; i++)
    #pragma unroll
    for (int j = 0; j < 2; j++) acc[i][j] = (f32x4){0.f, 0.f, 0.f, 0.f};
  int nbase = nb * 64;
  for (int c = 0; c < 147; c++) {
    int r = c / 3, sub = c - r * 3;
    int dy2 = r / 7 - 3, dx2 = r % 7 - 3;
    long long tap = ((long long)dy2 * P3 + dx2) * DIMC;
    __syncthreads();
    {
      const float* src = fvb + tap + sub * 64 + kq * 16;
      bf16x8 pk0, pk1;
      #pragma unroll
      for (int j = 0; j < 4; j++) {
        int ch = sub * 64 + kq * 16 + j * 4;
        float a = ap[r * 8 + ch / 24];
        float4 v = *(const float4*)(src + j * 4);
        short s0 = f2bf(v.x * a), s1 = f2bf(v.y * a), s2 = f2bf(v.z * a), s3 = f2bf(v.w * a);
        if (j < 2) {
          pk0[j * 4 + 0] = s0; pk0[j * 4 + 1] = s1; pk0[j * 4 + 2] = s2; pk0[j * 4 + 3] = s3;
        } else {
          pk1[(j - 2) * 4 + 0] = s0; pk1[(j - 2) * 4 + 1] = s1;
          pk1[(j - 2) * 4 + 2] = s2; pk1[(j - 2) * 4 + 3] = s3;
        }
      }
      *(bf16x8*)&As[arow][kq * 16] = pk0;
      *(bf16x8*)&As[arow][kq * 16 + 8] = pk1;
      const short* wp = w0t + (long long)(nbase + arow) * 9408 + c * 64 + kq * 16;
      *(bf16x8*)&Bs[arow][kq * 16] = *(const bf16x8*)wp;
      *(bf16x8*)&Bs[arow][kq * 16 + 8] = *(const bf16x8*)(wp + 8);
    }
    __syncthreads();
    #pragma unroll
    for (int kk = 0; kk < 2; kk++) {
      bf16x8 a0 = *(const bf16x8*)&As[wr * 32 + (lane & 15)][kk * 32 + (lane >> 4) * 8];
      bf16x8 a1 = *(const bf16x8*)&As[wr * 32 + 16 + (lane & 15)][kk * 32 + (lane >> 4) * 8];
      bf16x8 b0 = *(const bf16x8*)&Bs[wc * 32 + (lane & 15)][kk * 32 + (lane >> 4) * 8];
      bf16x8 b1 = *(const bf16x8*)&Bs[wc * 32 + 16 + (lane & 15)][kk * 32 + (lane >> 4) * 8];
      acc[0][0] = __builtin_amdgcn_mfma_f32_16x16x32_bf16(a0, b0, acc[0][0], 0, 0, 0);
      acc[0][1] = __builtin_amdgcn_mfma_f32_16x16x32_bf16(a0, b1, acc[0][1], 0, 0, 0);
      acc[1][0] = __builtin_amdgcn_mfma_f32_16x16x32_bf16(a1, b0, acc[1][0], 0, 0, 0);
      acc[1][1] = __builtin_amdgcn_mfma_f32_16x16x32_bf16(a1, b1, acc[1][1], 0, 0, 0);
    }
  }
  float rc0 = cell[b * 2 + 0] * 64.f, rc1 = cell[b * 2 + 1] * 64.f;
  int col0 = nbase + wc * 32 + (lane & 15);
  int row0 = wr * 32 + ((lane >> 4) << 2);
  #pragma unroll
  for (int nf = 0; nf < 2; nf++) {
    int n = col0 + nf * 16;
    float tailv = rc0 * w0[9408LL * 256 + n] + rc1 * w0[9409LL * 256 + n] + b0[n];
    #pragma unroll
    for (int mf = 0; mf < 2; mf++)
      #pragma unroll
      for (int i = 0; i < 4; i++)
        hout[(long long)(qbase + row0 + mf * 16 + i) * 256 + n] =
            fmaxf(acc[mf][nf][i] + tailv, 0.f);
  }
}

// h = [relu](hin[8192,256] @ w[256,256] + bias)  (fp32)
template <bool RELU>
__global__ __launch_bounds__(256) void k_fc(const float* __restrict__ hin,
                                            const float* __restrict__ w,
                                            const float* __restrict__ bias,
                                            float* __restrict__ hout) {
  int nb = blockIdx.x, mb = blockIdx.y;
  int qbase = mb * 64, nbase = nb * 64;
  int tid = threadIdx.x;
  int tx = tid & 15, ty = tid >> 4;
  __shared__ __align__(16) float As[16][64];
  __shared__ __align__(16) float Ws[16][64];
  float acc[4][4] = {};
  int ms = tid >> 2, js = tid & 3;
  int kw = tid >> 4, n4 = tid & 15;
  for (int kc = 0; kc < 16; kc++) {
    __syncthreads();
    float4 av = *(const float4*)(hin + ((long long)(qbase + ms)) * 256 + kc * 16 + js * 4);
    As[js * 4 + 0][ms] = av.x;
    As[js * 4 + 1][ms] = av.y;
    As[js * 4 + 2][ms] = av.z;
    As[js * 4 + 3][ms] = av.w;
    *(float4*)&Ws[kw][n4 * 4] =
        *(const float4*)(w + ((long long)(kc * 16 + kw)) * 256 + nbase + n4 * 4);
    __syncthreads();
    #pragma unroll
    for (int k = 0; k < 16; k++) {
      float4 a4 = *(const float4*)&As[k][ty * 4];
      float4 b4 = *(const float4*)&Ws[k][tx * 4];
      float aa[4] = {a4.x, a4.y, a4.z, a4.w};
      float bb[4] = {b4.x, b4.y, b4.z, b4.w};
      #pragma unroll
      for (int i = 0; i < 4; i++)
        #pragma unroll
        for (int j = 0; j < 4; j++) acc[i][j] += aa[i] * bb[j];
    }
  }
  #pragma unroll
  for (int i = 0; i < 4; i++) {
    float4 o;
    #pragma unroll
    for (int j = 0; j < 4; j++) {
      float v = acc[i][j] + bias[nbase + tx * 4 + j];
      if (RELU) v = fmaxf(v, 0.f);
      ((float*)&o)[j] = v;
    }
    *(float4*)(hout + ((long long)(qbase + ty * 4 + i)) * 256 + nbase + tx * 4) = o;
  }
}

// out = h3 @ m4w + m4b + bilinear(inp, border=True)
__global__ __launch_bounds__(64) void k_final(const float* __restrict__ h3,
                                              const float* __restrict__ w4,
                                              const float* __restrict__ b4,
                                              const float* __restrict__ sc,
                                              const float* __restrict__ inp,
                                              float* __restrict__ out) {
  int bq = blockIdx.x;
  int b = bq >> 12;
  int lane = threadIdx.x;
  float p0 = 0.f, p1 = 0.f, p2 = 0.f;
  const float* hr = h3 + (long long)bq * 256;
  #pragma unroll
  for (int u = 0; u < 4; u++) {
    int c = lane + u * 64;
    float hv = hr[c];
    p0 += hv * w4[c * 3 + 0];
    p1 += hv * w4[c * 3 + 1];
    p2 += hv * w4[c * 3 + 2];
  }
  #pragma unroll
  for (int s = 1; s < 64; s <<= 1) {
    p0 += __shfl_xor(p0, s);
    p1 += __shfl_xor(p1, s);
    p2 += __shfl_xor(p2, s);
  }
  if (lane == 0) {
    float cy = sc[bq * 2 + 0], cx = sc[bq * 2 + 1];
    float py = (cy + 1.f) * 32.f - 0.5f, px = (cx + 1.f) * 32.f - 0.5f;
    float fy = floorf(py), fx = floorf(px);
    float wy = py - fy, wx = px - fx;
    int y0 = (int)fy, x0 = (int)fx;
    int yc0 = min(max(y0, 0), 63), yc1 = min(max(y0 + 1, 0), 63);
    int xc0 = min(max(x0, 0), 63), xc1 = min(max(x0 + 1, 0), 63);
    float o[3] = {p0 + b4[0], p1 + b4[1], p2 + b4[2]};
    #pragma unroll
    for (int j = 0; j < 3; j++) {
      const float* im = inp + ((long long)b * 3 + j) * 4096;
      float s00 = im[yc0 * 64 + xc0], s01 = im[yc0 * 64 + xc1];
      float s10 = im[yc1 * 64 + xc0], s11 = im[yc1 * 64 + xc1];
      o[j] += (1.f - wy) * ((1.f - wx) * s00 + wx * s01) +
              wy * ((1.f - wx) * s10 + wx * s11);
      out[(long long)bq * 3 + j] = o[j];
    }
  }
}

extern "C" void kernel_launch(void* const* d_in, const int* in_sizes, int n_in,
                              void* d_out, int out_size, void* d_ws, size_t ws_size,
                              hipStream_t stream) {
  const float* inp = (const float*)d_in[0];
  const float* sc = (const float*)d_in[1];
  const float* cell = (const float*)d_in[2];
  const float* enc_w = (const float*)d_in[3];
  const float* enc_b = (const float*)d_in[4];
  const float* ch_w = (const float*)d_in[5];
  const float* ch_b = (const float*)d_in[6];
  const float* q_w = (const float*)d_in[7];
  const float* q_b = (const float*)d_in[8];
  const float* k_w = (const float*)d_in[9];
  const float* k_b = (const float*)d_in[10];
  const float* v_w = (const float*)d_in[11];
  const float* v_b = (const float*)d_in[12];
  const float* m0w = (const float*)d_in[13];
  const float* m0b = (const float*)d_in[14];
  const float* m1w = (const float*)d_in[15];
  const float* m1b = (const float*)d_in[16];
  const float* m2w = (const float*)d_in[17];
  const float* m2b = (const float*)d_in[18];
  const float* m3w = (const float*)d_in[19];
  const float* m3b = (const float*)d_in[20];
  const float* m4w = (const float*)d_in[21];
  const float* m4b = (const float*)d_in[22];
  float* ws = (float*)d_ws;
  float* f1p = ws + F_F1;
  float* featp = ws + F_FEAT;
  float* featqp = ws + F_FQ;
  float* featkp = ws + F_FK;
  float* featvp = ws + F_FV;
  float* attnb = ws + F_ATTN;
  float* h_a = ws + F_HA;
  float* h_b = ws + F_HB;
  short* w0t = (short*)(ws + F_W0T);
  short* wtb_ch = (short*)(ws + F_WTCHB);
  short* wtb_q = (short*)(ws + F_WTQB);
  short* wtb_k = (short*)(ws + F_WTKB);
  short* wtb_v = (short*)(ws + F_WTVB);
  float* outp = (float*)d_out;

  k_zero<<<2048, 256, 0, stream>>>((float4*)ws, (int)ZERO_N4);
  k_w0t<<<dim3(147, 4), 256, 0, stream>>>(m0w, w0t);
  k_wtb<<<(192 * 64 * 9 + 255) / 256, 256, 0, stream>>>(ch_w, wtb_ch, 64, 192);
  k_wtb<<<(192 * 192 * 9 + 255) / 256, 256, 0, stream>>>(q_w, wtb_q, 192, 192);
  k_wtb<<<(192 * 192 * 9 + 255) / 256, 256, 0, stream>>>(k_w, wtb_k, 192, 192);
  k_wtb<<<(192 * 192 * 9 + 255) / 256, 256, 0, stream>>>(v_w, wtb_v, 192, 192);
  k_conv1<<<(BB * 64 * 64 * ENC) / 256, 256, 0, stream>>>(inp, enc_w, enc_b, f1p);
  k_conv3x3m<64><<<dim3(3, BB * 64), 256, 0, stream>>>(f1p, wtb_ch, ch_b, featp, P1, 1, DIMC);
  k_conv3x3m<192><<<dim3(3, BB * 64), 256, 0, stream>>>(featp, wtb_q, q_b, featqp, P1, 1, DIMC);
  k_conv3x3m<192><<<dim3(3, BB * 64), 256, 0, stream>>>(featp, wtb_k, k_b, featkp, P3, 3, DIMC);
  k_conv3x3m<192><<<dim3(3, BB * 64), 256, 0, stream>>>(featp, wtb_v, v_b, featvp, P3, 3, DIMC);
  k_attn<<<BB * QQ, 64, 0, stream>>>(sc, featqp, featkp, attnb);
  k_l0m<<<dim3(4, 128), 256, 0, stream>>>(sc, cell, featvp, attnb, w0t, m0w, m0b, h_a);
  k_fc<true><<<dim3(4, 128), 256, 0, stream>>>(h_a, m1w, m1b, h_b);
  k_fc<true><<<dim3(4, 128), 256, 0, stream>>>(h_b, m2w, m2b, h_a);
  k_fc<true><<<dim3(4, 128), 256, 0, stream>>>(h_a, m3w, m3b, h_b);
  k_final<<<BB * QQ, 64, 0, stream>>>(h_b, m4w, m4b, sc, inp, outp);
}

// Round 5
// 480.632 us; speedup vs baseline: 1.0895x; 1.0895x over previous
//
#include <hip/hip_runtime.h>
#include <hip/hip_bf16.h>

// ---------------------------------------------------------------------------
// Round 4 (= round 3 resubmitted after audit): K/V feature maps stored as
// bf16 (3.76 MB each -> per-XCD-L2 resident) to kill the 318 MB L2-miss
// gather stream seen in k_l0m (and the same pattern in k_attn).
//   k_zero -> k_w0t + k_wtb x4 -> k_conv1 -> k_conv3x3m (ch,q fp32; k,v bf16)
//   -> k_attn (bf16 K gather) -> k_l0m (bf16 V gather, XCD swizzle)
//   -> k_fc x3 -> k_final.
// ---------------------------------------------------------------------------

constexpr int BB = 2, QQ = 4096, DIMC = 192, RAW = 49;
constexpr int ENC = 64, P1 = 66, P3 = 70;

typedef __attribute__((ext_vector_type(8))) short bf16x8;
typedef __attribute__((ext_vector_type(8))) unsigned short u16x8;
typedef __attribute__((ext_vector_type(4))) float f32x4;

__device__ inline short f2bf(float f) {
  __hip_bfloat16 h = __float2bfloat16(f);
  return __builtin_bit_cast(short, h);
}
__device__ inline float bf2f(unsigned short u) {
  return __uint_as_float(((unsigned)u) << 16);
}

// ws offsets in float units
constexpr long long N_F1 = (long long)BB * P1 * P1 * ENC;     // 557568
constexpr long long N_FT = (long long)BB * P1 * P1 * DIMC;    // 1672704
constexpr long long N_FKS = (long long)BB * P3 * P3 * DIMC;   // shorts: 1881600
constexpr long long F_F1 = 0;
constexpr long long F_FEAT = F_F1 + N_F1;
constexpr long long F_FQ = F_FEAT + N_FT;
constexpr long long F_FKB = F_FQ + N_FT;            // bf16 K map
constexpr long long F_FVB = F_FKB + N_FKS / 2;      // bf16 V map
constexpr long long F_ZEND = F_FVB + N_FKS / 2;     // zero region end
constexpr long long F_ATTN = F_ZEND;
constexpr long long F_HA = F_ATTN + (long long)BB * QQ * RAW * 8;
constexpr long long F_HB = F_HA + 8192LL * 256;
constexpr long long F_W0T = F_HB + 8192LL * 256;
constexpr long long F_WTCHB = F_W0T + (256LL * 9408) / 2;
constexpr long long F_WTQB = F_WTCHB + (192LL * 576) / 2;
constexpr long long F_WTKB = F_WTQB + (192LL * 1728) / 2;
constexpr long long F_WTVB = F_WTKB + (192LL * 1728) / 2;
constexpr long long ZERO_N4 = F_ZEND / 4;

__global__ __launch_bounds__(256) void k_zero(float4* p, int n4) {
  int i = blockIdx.x * 256 + threadIdx.x;
  float4 z = make_float4(0.f, 0.f, 0.f, 0.f);
  for (; i < n4; i += gridDim.x * 256) p[i] = z;
}

// w0 [9408+2][256] fp32 -> w0t [256][9408] bf16 (LDS tile transpose)
__global__ __launch_bounds__(256) void k_w0t(const float* __restrict__ w0,
                                             short* __restrict__ w0t) {
  __shared__ short sh[64][72];
  int k0 = blockIdx.x * 64, n0 = blockIdx.y * 64;
  int t = threadIdx.x;
  #pragma unroll
  for (int i = 0; i < 16; i++) {
    int idx = t + i * 256;
    int r = idx >> 6, cc = idx & 63;
    sh[cc][r] = f2bf(w0[(long long)(k0 + r) * 256 + n0 + cc]);
  }
  __syncthreads();
  #pragma unroll
  for (int i = 0; i < 16; i++) {
    int idx = t + i * 256;
    int n = idx >> 6, k = idx & 63;
    w0t[(long long)(n0 + n) * 9408 + k0 + k] = sh[n][k];
  }
}

// conv w [CO][CI][3][3] fp32 -> wtb [CO][9*CI] bf16 with k = tap*CI + ci
__global__ __launch_bounds__(256) void k_wtb(const float* __restrict__ w,
                                             short* __restrict__ wtb, int CI, int CO) {
  int g = blockIdx.x * 256 + threadIdx.x;
  if (g >= CO * CI * 9) return;
  int co = g / (CI * 9);
  int r = g - co * CI * 9;
  int ci = r / 9, t = r - ci * 9;
  wtb[(long long)co * (9 * CI) + t * CI + ci] = f2bf(w[g]);
}

// inp [B][3][64][64] -> f1p [B][66][66][64] interior (fp32, tiny)
__global__ __launch_bounds__(256) void k_conv1(const float* __restrict__ inp,
                                               const float* __restrict__ ew,
                                               const float* __restrict__ eb,
                                               float* __restrict__ f1p) {
  int g = blockIdx.x * 256 + threadIdx.x;
  int co = g & 63, x = (g >> 6) & 63, y = (g >> 12) & 63, b = g >> 18;
  float acc = eb[co];
  #pragma unroll
  for (int ci = 0; ci < 3; ci++)
    #pragma unroll
    for (int ky = 0; ky < 3; ky++) {
      int yy = y + ky - 1;
      if (yy < 0 || yy > 63) continue;
      #pragma unroll
      for (int kx = 0; kx < 3; kx++) {
        int xx = x + kx - 1;
        if (xx < 0 || xx > 63) continue;
        acc += inp[((b * 3 + ci) * 64 + yy) * 64 + xx] * ew[((co * 3 + ci) * 3 + ky) * 3 + kx];
      }
    }
  f1p[((b * P1 + y + 1) * P1 + (x + 1)) * ENC + co] = acc;
}

// MFMA 3x3 conv: in [B][66][66][CIN] fp32 padded; wtb [CO][9*CIN] bf16.
// OB16: write bf16 output map (for K/V) else fp32.
template <int CIN, bool OB16>
__global__ __launch_bounds__(256) void k_conv3x3m(const float* __restrict__ in,
                                                  const short* __restrict__ wtb,
                                                  const float* __restrict__ bias,
                                                  void* __restrict__ outv, int pitchO,
                                                  int padO, int COUT) {
  constexpr int NCH = CIN / 64;
  int nb = blockIdx.x;
  int by = blockIdx.y;
  int b = by >> 6, y = by & 63;
  int t = threadIdx.x;
  int lane = t & 63, w = t >> 6, wr = w >> 1, wc = w & 1;
  __shared__ __align__(16) short As[64][72];
  __shared__ __align__(16) short Bs[64][72];
  f32x4 acc[2][2];
  #pragma unroll
  for (int i = 0; i < 2; i++)
    #pragma unroll
    for (int j = 0; j < 2; j++) acc[i][j] = (f32x4){0.f, 0.f, 0.f, 0.f};
  int arow = t >> 2, kq = t & 3;
  int nbase = nb * 64;
  const long long K9 = 9LL * CIN;
  for (int c = 0; c < 9 * NCH; c++) {
    int t9 = c / NCH, sub = c - t9 * NCH;
    int dy = t9 / 3 - 1, dx = t9 % 3 - 1;
    __syncthreads();
    {
      const float* src = in + (((long long)b * P1 + y + dy + 1) * P1 + (arow + dx + 1)) * CIN +
                         sub * 64 + kq * 16;
      bf16x8 pk0, pk1;
      #pragma unroll
      for (int j = 0; j < 2; j++) {
        float4 v = *(const float4*)(src + j * 4);
        pk0[j * 4 + 0] = f2bf(v.x);
        pk0[j * 4 + 1] = f2bf(v.y);
        pk0[j * 4 + 2] = f2bf(v.z);
        pk0[j * 4 + 3] = f2bf(v.w);
      }
      #pragma unroll
      for (int j = 0; j < 2; j++) {
        float4 v = *(const float4*)(src + 8 + j * 4);
        pk1[j * 4 + 0] = f2bf(v.x);
        pk1[j * 4 + 1] = f2bf(v.y);
        pk1[j * 4 + 2] = f2bf(v.z);
        pk1[j * 4 + 3] = f2bf(v.w);
      }
      *(bf16x8*)&As[arow][kq * 16] = pk0;
      *(bf16x8*)&As[arow][kq * 16 + 8] = pk1;
      const short* wp = wtb + (long long)(nbase + arow) * K9 + c * 64 + kq * 16;
      *(bf16x8*)&Bs[arow][kq * 16] = *(const bf16x8*)wp;
      *(bf16x8*)&Bs[arow][kq * 16 + 8] = *(const bf16x8*)(wp + 8);
    }
    __syncthreads();
    #pragma unroll
    for (int kk = 0; kk < 2; kk++) {
      bf16x8 a0 = *(const bf16x8*)&As[wr * 32 + (lane & 15)][kk * 32 + (lane >> 4) * 8];
      bf16x8 a1 = *(const bf16x8*)&As[wr * 32 + 16 + (lane & 15)][kk * 32 + (lane >> 4) * 8];
      bf16x8 b0 = *(const bf16x8*)&Bs[wc * 32 + (lane & 15)][kk * 32 + (lane >> 4) * 8];
      bf16x8 b1 = *(const bf16x8*)&Bs[wc * 32 + 16 + (lane & 15)][kk * 32 + (lane >> 4) * 8];
      acc[0][0] = __builtin_amdgcn_mfma_f32_16x16x32_bf16(a0, b0, acc[0][0], 0, 0, 0);
      acc[0][1] = __builtin_amdgcn_mfma_f32_16x16x32_bf16(a0, b1, acc[0][1], 0, 0, 0);
      acc[1][0] = __builtin_amdgcn_mfma_f32_16x16x32_bf16(a1, b0, acc[1][0], 0, 0, 0);
      acc[1][1] = __builtin_amdgcn_mfma_f32_16x16x32_bf16(a1, b1, acc[1][1], 0, 0, 0);
    }
  }
  int col0 = nbase + wc * 32 + (lane & 15);
  int row0 = wr * 32 + ((lane >> 4) << 2);
  #pragma unroll
  for (int nf = 0; nf < 2; nf++) {
    int co = col0 + nf * 16;
    float bv = bias[co];
    #pragma unroll
    for (int mf = 0; mf < 2; mf++)
      #pragma unroll
      for (int i = 0; i < 4; i++) {
        int x = row0 + mf * 16 + i;
        long long oi = (((long long)b * pitchO + y + padO) * pitchO + (x + padO)) * COUT + co;
        float val = acc[mf][nf][i] + bv;
        if (OB16) ((short*)outv)[oi] = f2bf(val);
        else ((float*)outv)[oi] = val;
      }
  }
}

// per-query attention probs: attnO[bq][49][8]; K map bf16
__global__ __launch_bounds__(64) void k_attn(const float* __restrict__ sc,
                                             const float* __restrict__ fq,
                                             const unsigned short* __restrict__ fkb,
                                             float* __restrict__ attnO) {
  int bq = blockIdx.x;
  int b = bq >> 12;
  int lane = threadIdx.x;
  float cy = sc[bq * 2 + 0], cx = sc[bq * 2 + 1];
  float py = (cy + 1.f) * 32.f - 0.5f, px = (cx + 1.f) * 32.f - 0.5f;
  float fy = floorf(py), fx = floorf(px);
  float wy = py - fy, wx = px - fx;
  int iy = (int)fy, ix = (int)fx;
  __shared__ __align__(16) float qv[192];
  {
    const float* base = fq + (((long long)b * P1 + iy + 1) * P1 + (ix + 1)) * DIMC;
    #pragma unroll
    for (int u = 0; u < 3; u++) {
      int c = lane * 3 + u;
      float v00 = base[c], v01 = base[DIMC + c];
      float v10 = base[P1 * DIMC + c], v11 = base[P1 * DIMC + DIMC + c];
      qv[c] = (1.f - wy) * ((1.f - wx) * v00 + wx * v01) +
              wy * ((1.f - wx) * v10 + wx * v11);
    }
  }
  __syncthreads();
  int icy = min(max((int)floorf(py + 0.5f), 0), 63);
  int icx = min(max((int)floorf(px + 0.5f), 0), 63);
  float l[8];
  #pragma unroll
  for (int h = 0; h < 8; h++) l[h] = -1e30f;
  if (lane < 49) {
    int dy = lane / 7 - 3, dx = lane % 7 - 3;
    const unsigned short* kb =
        fkb + (((long long)b * P3 + icy + dy + 3) * P3 + (icx + dx + 3)) * DIMC;
    #pragma unroll
    for (int h = 0; h < 8; h++) l[h] = 0.f;
    #pragma unroll
    for (int c8 = 0; c8 < 24; c8++) {  // 8 ch per iter; 24ch head = 3 iters
      u16x8 k8 = *(const u16x8*)(kb + c8 * 8);
      float4 qa = *(const float4*)&qv[c8 * 8];
      float4 qb = *(const float4*)&qv[c8 * 8 + 4];
      l[c8 / 3] += qa.x * bf2f(k8[0]) + qa.y * bf2f(k8[1]) + qa.z * bf2f(k8[2]) +
                   qa.w * bf2f(k8[3]) + qb.x * bf2f(k8[4]) + qb.y * bf2f(k8[5]) +
                   qb.z * bf2f(k8[6]) + qb.w * bf2f(k8[7]);
    }
    const float s = 0.20412414523193154f;  // 1/sqrt(24)
    #pragma unroll
    for (int h = 0; h < 8; h++) l[h] *= s;
  }
  float a[8];
  #pragma unroll
  for (int h = 0; h < 8; h++) {
    float mx = l[h];
    #pragma unroll
    for (int s = 1; s < 64; s <<= 1) mx = fmaxf(mx, __shfl_xor(mx, s));
    float e = (lane < 49) ? expf(l[h] - mx) : 0.f;
    float sm = e;
    #pragma unroll
    for (int s = 1; s < 64; s <<= 1) sm += __shfl_xor(sm, s);
    a[h] = e / sm;
  }
  if (lane < 49) {
    float* op = attnO + ((long long)bq * 49 + lane) * 8;
    *(float4*)op = make_float4(a[0], a[1], a[2], a[3]);
    *(float4*)(op + 4) = make_float4(a[4], a[5], a[6], a[7]);
  }
}

// MFMA fused gather+attn-weight GEMM: h = relu(A[8192,9408] @ w0t^T + tail)
// V map bf16; XCD-swizzled block mapping (bijective, 512 blocks).
__global__ __launch_bounds__(256) void k_l0m(const float* __restrict__ sc,
                                             const float* __restrict__ cell,
                                             const unsigned short* __restrict__ fvb,
                                             const float* __restrict__ attn,
                                             const short* __restrict__ w0t,
                                             const float* __restrict__ w0,
                                             const float* __restrict__ b0,
                                             float* __restrict__ hout) {
  int lin = blockIdx.y * 4 + blockIdx.x;          // 0..511
  int swz = (lin & 7) * 64 + (lin >> 3);          // bijective XCD chunking
  int nb = swz & 3, mb = swz >> 2;
  int qbase = mb * 64;
  int b = qbase >> 12;
  int t = threadIdx.x;
  int lane = t & 63, w = t >> 6, wr = w >> 1, wc = w & 1;
  __shared__ __align__(16) short As[64][72];
  __shared__ __align__(16) short Bs[64][72];
  int arow = t >> 2, kq = t & 3;
  int q = qbase + arow;
  float cy = sc[q * 2 + 0], cx = sc[q * 2 + 1];
  float py = (cy + 1.f) * 32.f - 0.5f, px = (cx + 1.f) * 32.f - 0.5f;
  int icy = min(max((int)floorf(py + 0.5f), 0), 63);
  int icx = min(max((int)floorf(px + 0.5f), 0), 63);
  const unsigned short* fvp = fvb + (((long long)b * P3 + icy + 3) * P3 + (icx + 3)) * DIMC;
  const float* ap = attn + (long long)q * 49 * 8;
  f32x4 acc[2][2];
  #pragma unroll
  for (int i = 0; i < 2; i++)
    #pragma unroll
    for (int j = 0; j < 2; j++) acc[i][j] = (f32x4){0.f, 0.f, 0.f, 0.f};
  int nbase = nb * 64;
  for (int c = 0; c < 147; c++) {
    int r = c / 3, sub = c - r * 3;
    int dy2 = r / 7 - 3, dx2 = r % 7 - 3;
    long long tap = ((long long)dy2 * P3 + dx2) * DIMC;
    __syncthreads();
    {
      const unsigned short* src = fvp + tap + sub * 64 + kq * 16;
      u16x8 r0 = *(const u16x8*)src;
      u16x8 r1 = *(const u16x8*)(src + 8);
      bf16x8 pk0, pk1;
      #pragma unroll
      for (int j = 0; j < 2; j++) {
        float a = ap[r * 8 + (sub * 64 + kq * 16 + j * 4) / 24];
        #pragma unroll
        for (int e = 0; e < 4; e++) pk0[j * 4 + e] = f2bf(bf2f(r0[j * 4 + e]) * a);
      }
      #pragma unroll
      for (int j = 2; j < 4; j++) {
        float a = ap[r * 8 + (sub * 64 + kq * 16 + j * 4) / 24];
        #pragma unroll
        for (int e = 0; e < 4; e++) pk1[(j - 2) * 4 + e] = f2bf(bf2f(r1[(j - 2) * 4 + e]) * a);
      }
      *(bf16x8*)&As[arow][kq * 16] = pk0;
      *(bf16x8*)&As[arow][kq * 16 + 8] = pk1;
      const short* wp = w0t + (long long)(nbase + arow) * 9408 + c * 64 + kq * 16;
      *(bf16x8*)&Bs[arow][kq * 16] = *(const bf16x8*)wp;
      *(bf16x8*)&Bs[arow][kq * 16 + 8] = *(const bf16x8*)(wp + 8);
    }
    __syncthreads();
    #pragma unroll
    for (int kk = 0; kk < 2; kk++) {
      bf16x8 a0 = *(const bf16x8*)&As[wr * 32 + (lane & 15)][kk * 32 + (lane >> 4) * 8];
      bf16x8 a1 = *(const bf16x8*)&As[wr * 32 + 16 + (lane & 15)][kk * 32 + (lane >> 4) * 8];
      bf16x8 b0 = *(const bf16x8*)&Bs[wc * 32 + (lane & 15)][kk * 32 + (lane >> 4) * 8];
      bf16x8 b1 = *(const bf16x8*)&Bs[wc * 32 + 16 + (lane & 15)][kk * 32 + (lane >> 4) * 8];
      acc[0][0] = __builtin_amdgcn_mfma_f32_16x16x32_bf16(a0, b0, acc[0][0], 0, 0, 0);
      acc[0][1] = __builtin_amdgcn_mfma_f32_16x16x32_bf16(a0, b1, acc[0][1], 0, 0, 0);
      acc[1][0] = __builtin_amdgcn_mfma_f32_16x16x32_bf16(a1, b0, acc[1][0], 0, 0, 0);
      acc[1][1] = __builtin_amdgcn_mfma_f32_16x16x32_bf16(a1, b1, acc[1][1], 0, 0, 0);
    }
  }
  float rc0 = cell[b * 2 + 0] * 64.f, rc1 = cell[b * 2 + 1] * 64.f;
  int col0 = nbase + wc * 32 + (lane & 15);
  int row0 = wr * 32 + ((lane >> 4) << 2);
  #pragma unroll
  for (int nf = 0; nf < 2; nf++) {
    int n = col0 + nf * 16;
    float tailv = rc0 * w0[9408LL * 256 + n] + rc1 * w0[9409LL * 256 + n] + b0[n];
    #pragma unroll
    for (int mf = 0; mf < 2; mf++)
      #pragma unroll
      for (int i = 0; i < 4; i++)
        hout[(long long)(qbase + row0 + mf * 16 + i) * 256 + n] =
            fmaxf(acc[mf][nf][i] + tailv, 0.f);
  }
}

// h = [relu](hin[8192,256] @ w[256,256] + bias)  (fp32)
template <bool RELU>
__global__ __launch_bounds__(256) void k_fc(const float* __restrict__ hin,
                                            const float* __restrict__ w,
                                            const float* __restrict__ bias,
                                            float* __restrict__ hout) {
  int nb = blockIdx.x, mb = blockIdx.y;
  int qbase = mb * 64, nbase = nb * 64;
  int tid = threadIdx.x;
  int tx = tid & 15, ty = tid >> 4;
  __shared__ __align__(16) float As[16][64];
  __shared__ __align__(16) float Ws[16][64];
  float acc[4][4] = {};
  int ms = tid >> 2, js = tid & 3;
  int kw = tid >> 4, n4 = tid & 15;
  for (int kc = 0; kc < 16; kc++) {
    __syncthreads();
    float4 av = *(const float4*)(hin + ((long long)(qbase + ms)) * 256 + kc * 16 + js * 4);
    As[js * 4 + 0][ms] = av.x;
    As[js * 4 + 1][ms] = av.y;
    As[js * 4 + 2][ms] = av.z;
    As[js * 4 + 3][ms] = av.w;
    *(float4*)&Ws[kw][n4 * 4] =
        *(const float4*)(w + ((long long)(kc * 16 + kw)) * 256 + nbase + n4 * 4);
    __syncthreads();
    #pragma unroll
    for (int k = 0; k < 16; k++) {
      float4 a4 = *(const float4*)&As[k][ty * 4];
      float4 b4 = *(const float4*)&Ws[k][tx * 4];
      float aa[4] = {a4.x, a4.y, a4.z, a4.w};
      float bb[4] = {b4.x, b4.y, b4.z, b4.w};
      #pragma unroll
      for (int i = 0; i < 4; i++)
        #pragma unroll
        for (int j = 0; j < 4; j++) acc[i][j] += aa[i] * bb[j];
    }
  }
  #pragma unroll
  for (int i = 0; i < 4; i++) {
    float4 o;
    #pragma unroll
    for (int j = 0; j < 4; j++) {
      float v = acc[i][j] + bias[nbase + tx * 4 + j];
      if (RELU) v = fmaxf(v, 0.f);
      ((float*)&o)[j] = v;
    }
    *(float4*)(hout + ((long long)(qbase + ty * 4 + i)) * 256 + nbase + tx * 4) = o;
  }
}

// out = h3 @ m4w + m4b + bilinear(inp, border=True)
__global__ __launch_bounds__(64) void k_final(const float* __restrict__ h3,
                                              const float* __restrict__ w4,
                                              const float* __restrict__ b4,
                                              const float* __restrict__ sc,
                                              const float* __restrict__ inp,
                                              float* __restrict__ out) {
  int bq = blockIdx.x;
  int b = bq >> 12;
  int lane = threadIdx.x;
  float p0 = 0.f, p1 = 0.f, p2 = 0.f;
  const float* hr = h3 + (long long)bq * 256;
  #pragma unroll
  for (int u = 0; u < 4; u++) {
    int c = lane + u * 64;
    float hv = hr[c];
    p0 += hv * w4[c * 3 + 0];
    p1 += hv * w4[c * 3 + 1];
    p2 += hv * w4[c * 3 + 2];
  }
  #pragma unroll
  for (int s = 1; s < 64; s <<= 1) {
    p0 += __shfl_xor(p0, s);
    p1 += __shfl_xor(p1, s);
    p2 += __shfl_xor(p2, s);
  }
  if (lane == 0) {
    float cy = sc[bq * 2 + 0], cx = sc[bq * 2 + 1];
    float py = (cy + 1.f) * 32.f - 0.5f, px = (cx + 1.f) * 32.f - 0.5f;
    float fy = floorf(py), fx = floorf(px);
    float wy = py - fy, wx = px - fx;
    int y0 = (int)fy, x0 = (int)fx;
    int yc0 = min(max(y0, 0), 63), yc1 = min(max(y0 + 1, 0), 63);
    int xc0 = min(max(x0, 0), 63), xc1 = min(max(x0 + 1, 0), 63);
    float o[3] = {p0 + b4[0], p1 + b4[1], p2 + b4[2]};
    #pragma unroll
    for (int j = 0; j < 3; j++) {
      const float* im = inp + ((long long)b * 3 + j) * 4096;
      float s00 = im[yc0 * 64 + xc0], s01 = im[yc0 * 64 + xc1];
      float s10 = im[yc1 * 64 + xc0], s11 = im[yc1 * 64 + xc1];
      o[j] += (1.f - wy) * ((1.f - wx) * s00 + wx * s01) +
              wy * ((1.f - wx) * s10 + wx * s11);
      out[(long long)bq * 3 + j] = o[j];
    }
  }
}

extern "C" void kernel_launch(void* const* d_in, const int* in_sizes, int n_in,
                              void* d_out, int out_size, void* d_ws, size_t ws_size,
                              hipStream_t stream) {
  const float* inp = (const float*)d_in[0];
  const float* sc = (const float*)d_in[1];
  const float* cell = (const float*)d_in[2];
  const float* enc_w = (const float*)d_in[3];
  const float* enc_b = (const float*)d_in[4];
  const float* ch_w = (const float*)d_in[5];
  const float* ch_b = (const float*)d_in[6];
  const float* q_w = (const float*)d_in[7];
  const float* q_b = (const float*)d_in[8];
  const float* k_w = (const float*)d_in[9];
  const float* k_b = (const float*)d_in[10];
  const float* v_w = (const float*)d_in[11];
  const float* v_b = (const float*)d_in[12];
  const float* m0w = (const float*)d_in[13];
  const float* m0b = (const float*)d_in[14];
  const float* m1w = (const float*)d_in[15];
  const float* m1b = (const float*)d_in[16];
  const float* m2w = (const float*)d_in[17];
  const float* m2b = (const float*)d_in[18];
  const float* m3w = (const float*)d_in[19];
  const float* m3b = (const float*)d_in[20];
  const float* m4w = (const float*)d_in[21];
  const float* m4b = (const float*)d_in[22];
  float* ws = (float*)d_ws;
  float* f1p = ws + F_F1;
  float* featp = ws + F_FEAT;
  float* featqp = ws + F_FQ;
  unsigned short* fkb = (unsigned short*)(ws + F_FKB);
  unsigned short* fvb = (unsigned short*)(ws + F_FVB);
  float* attnb = ws + F_ATTN;
  float* h_a = ws + F_HA;
  float* h_b = ws + F_HB;
  short* w0t = (short*)(ws + F_W0T);
  short* wtb_ch = (short*)(ws + F_WTCHB);
  short* wtb_q = (short*)(ws + F_WTQB);
  short* wtb_k = (short*)(ws + F_WTKB);
  short* wtb_v = (short*)(ws + F_WTVB);
  float* outp = (float*)d_out;

  k_zero<<<2048, 256, 0, stream>>>((float4*)ws, (int)ZERO_N4);
  k_w0t<<<dim3(147, 4), 256, 0, stream>>>(m0w, w0t);
  k_wtb<<<(192 * 64 * 9 + 255) / 256, 256, 0, stream>>>(ch_w, wtb_ch, 64, 192);
  k_wtb<<<(192 * 192 * 9 + 255) / 256, 256, 0, stream>>>(q_w, wtb_q, 192, 192);
  k_wtb<<<(192 * 192 * 9 + 255) / 256, 256, 0, stream>>>(k_w, wtb_k, 192, 192);
  k_wtb<<<(192 * 192 * 9 + 255) / 256, 256, 0, stream>>>(v_w, wtb_v, 192, 192);
  k_conv1<<<(BB * 64 * 64 * ENC) / 256, 256, 0, stream>>>(inp, enc_w, enc_b, f1p);
  k_conv3x3m<64, false><<<dim3(3, BB * 64), 256, 0, stream>>>(f1p, wtb_ch, ch_b, featp, P1, 1, DIMC);
  k_conv3x3m<192, false><<<dim3(3, BB * 64), 256, 0, stream>>>(featp, wtb_q, q_b, featqp, P1, 1, DIMC);
  k_conv3x3m<192, true><<<dim3(3, BB * 64), 256, 0, stream>>>(featp, wtb_k, k_b, fkb, P3, 3, DIMC);
  k_conv3x3m<192, true><<<dim3(3, BB * 64), 256, 0, stream>>>(featp, wtb_v, v_b, fvb, P3, 3, DIMC);
  k_attn<<<BB * QQ, 64, 0, stream>>>(sc, featqp, fkb, attnb);
  k_l0m<<<dim3(4, 128), 256, 0, stream>>>(sc, cell, fvb, attnb, w0t, m0w, m0b, h_a);
  k_fc<true><<<dim3(4, 128), 256, 0, stream>>>(h_a, m1w, m1b, h_b);
  k_fc<true><<<dim3(4, 128), 256, 0, stream>>>(h_b, m2w, m2b, h_a);
  k_fc<true><<<dim3(4, 128), 256, 0, stream>>>(h_a, m3w, m3b, h_b);
  k_final<<<BB * QQ, 64, 0, stream>>>(h_b, m4w, m4b, sc, inp, outp);
}

// Round 7
// 386.150 us; speedup vs baseline: 1.3561x; 1.2447x over previous
//
#include <hip/hip_runtime.h>
#include <hip/hip_bf16.h>

// ---------------------------------------------------------------------------
// Round 7 (= round 5 resubmitted after audit): k_l0m restructured (64q x 128n
// x K/2 blocks, fp32 partials + reduce) to cut A-conversion duplication
// 4x->2x and double MFMA per barrier. fc layers -> bf16 MFMA (h stored bf16).
// featp/f1p bf16 (numerically neutral). attnb bf16. ws 46.5MB.
// ---------------------------------------------------------------------------

constexpr int BB = 2, QQ = 4096, DIMC = 192, RAW = 49;
constexpr int ENC = 64, P1 = 66, P3 = 70;

typedef __attribute__((ext_vector_type(8))) short bf16x8;
typedef __attribute__((ext_vector_type(8))) unsigned short u16x8;
typedef __attribute__((ext_vector_type(4))) float f32x4;

__device__ inline short f2bf(float f) {
  __hip_bfloat16 h = __float2bfloat16(f);
  return __builtin_bit_cast(short, h);
}
__device__ inline float bf2f(unsigned short u) {
  return __uint_as_float(((unsigned)u) << 16);
}

// ---- ws layout (float units) ----
constexpr long long F_F1 = 0;                 // f1p bf16: 557568 sh
constexpr long long F_FEAT = 278784;          // featp bf16: 1672704 sh
constexpr long long F_FQ = 1115136;           // featqp f32: 1672704 f
constexpr long long ZA_END = 2787840;
constexpr long long F_PART = 0;               // 2 x 8192*256 f32 = 4194304 f
constexpr long long F_FKB = 4194304;          // fkb bf16: 1881600 sh
constexpr long long F_FVB = 5135104;          // fvb bf16
constexpr long long F_ATTN = 6075904;         // attnb bf16: 3211264 sh
constexpr long long F_W0T = 7681536;          // w0t bf16 [256][9408]
constexpr long long F_WTCH = 8885760;         // 110592 sh
constexpr long long F_WTQ = 8941056;          // 331776 sh
constexpr long long F_WTK = 9106944;
constexpr long long F_WTV = 9272832;
constexpr long long F_WFC1 = 9438720;         // [256][256] sh
constexpr long long F_WFC2 = 9471488;
constexpr long long F_WFC3 = 9504256;
constexpr long long F_HA = 9537024;           // h bf16: 2097152 sh
constexpr long long F_HB = 10585600;          // end 11634176 f = 46.5MB

__global__ __launch_bounds__(256) void k_zero(float4* p, int n4) {
  int i = blockIdx.x * 256 + threadIdx.x;
  float4 z = make_float4(0.f, 0.f, 0.f, 0.f);
  for (; i < n4; i += gridDim.x * 256) p[i] = z;
}

// w0 [9410][256] fp32 -> w0t [256][9408] bf16
__global__ __launch_bounds__(256) void k_w0t(const float* __restrict__ w0,
                                             short* __restrict__ w0t) {
  __shared__ short sh[64][72];
  int k0 = blockIdx.x * 64, n0 = blockIdx.y * 64;
  int t = threadIdx.x;
  #pragma unroll
  for (int i = 0; i < 16; i++) {
    int idx = t + i * 256;
    int r = idx >> 6, cc = idx & 63;
    sh[cc][r] = f2bf(w0[(long long)(k0 + r) * 256 + n0 + cc]);
  }
  __syncthreads();
  #pragma unroll
  for (int i = 0; i < 16; i++) {
    int idx = t + i * 256;
    int n = idx >> 6, k = idx & 63;
    w0t[(long long)(n0 + n) * 9408 + k0 + k] = sh[n][k];
  }
}

// conv w [CO][CI][3][3] fp32 -> wtb [CO][9*CI] bf16, k = tap*CI + ci
__global__ __launch_bounds__(256) void k_wtb(const float* __restrict__ w,
                                             short* __restrict__ wtb, int CI, int CO) {
  int g = blockIdx.x * 256 + threadIdx.x;
  if (g >= CO * CI * 9) return;
  int co = g / (CI * 9);
  int r = g - co * CI * 9;
  int ci = r / 9, t = r - ci * 9;
  wtb[(long long)co * (9 * CI) + t * CI + ci] = f2bf(w[g]);
}

// fc w [256][256] fp32 (k-major) -> wt [n][k] bf16
__global__ __launch_bounds__(256) void k_wfc(const float* __restrict__ w,
                                             short* __restrict__ wt) {
  int n = blockIdx.x, k = threadIdx.x;
  wt[n * 256 + k] = f2bf(w[k * 256 + n]);
}

// inp [B][3][64][64] fp32 -> f1p [B][66][66][64] bf16 interior
__global__ __launch_bounds__(256) void k_conv1(const float* __restrict__ inp,
                                               const float* __restrict__ ew,
                                               const float* __restrict__ eb,
                                               unsigned short* __restrict__ f1p) {
  int g = blockIdx.x * 256 + threadIdx.x;
  int co = g & 63, x = (g >> 6) & 63, y = (g >> 12) & 63, b = g >> 18;
  float acc = eb[co];
  #pragma unroll
  for (int ci = 0; ci < 3; ci++)
    #pragma unroll
    for (int ky = 0; ky < 3; ky++) {
      int yy = y + ky - 1;
      if (yy < 0 || yy > 63) continue;
      #pragma unroll
      for (int kx = 0; kx < 3; kx++) {
        int xx = x + kx - 1;
        if (xx < 0 || xx > 63) continue;
        acc += inp[((b * 3 + ci) * 64 + yy) * 64 + xx] * ew[((co * 3 + ci) * 3 + ky) * 3 + kx];
      }
    }
  f1p[((b * P1 + y + 1) * P1 + (x + 1)) * ENC + co] = (unsigned short)f2bf(acc);
}

// MFMA 3x3 conv: in bf16 [B][66][66][CIN]; wtb [192][9*CIN] bf16.
// OF32: write f32 output (featqp) else bf16.
template <int CIN, bool OF32>
__global__ __launch_bounds__(256) void k_conv3x3m(const unsigned short* __restrict__ in,
                                                  const short* __restrict__ wtb,
                                                  const float* __restrict__ bias,
                                                  void* __restrict__ outv, int pitchO,
                                                  int padO) {
  constexpr int NCH = CIN / 64;
  int nb = blockIdx.x;
  int by = blockIdx.y;
  int b = by >> 6, y = by & 63;
  int t = threadIdx.x;
  int lane = t & 63, w = t >> 6, wr = w >> 1, wc = w & 1;
  __shared__ __align__(16) short As[64][72];
  __shared__ __align__(16) short Bs[64][72];
  f32x4 acc[2][2];
  #pragma unroll
  for (int i = 0; i < 2; i++)
    #pragma unroll
    for (int j = 0; j < 2; j++) acc[i][j] = (f32x4){0.f, 0.f, 0.f, 0.f};
  int arow = t >> 2, kq4 = t & 3;
  int nbase = nb * 64;
  const long long K9 = 9LL * CIN;
  for (int c = 0; c < 9 * NCH; c++) {
    int t9 = c / NCH, sub = c - t9 * NCH;
    int dy = t9 / 3 - 1, dx = t9 % 3 - 1;
    __syncthreads();
    {
      const unsigned short* src = in +
          (((long long)b * P1 + y + dy + 1) * P1 + (arow + dx + 1)) * CIN + sub * 64 + kq4 * 16;
      *(bf16x8*)&As[arow][kq4 * 16] = *(const bf16x8*)src;
      *(bf16x8*)&As[arow][kq4 * 16 + 8] = *(const bf16x8*)(src + 8);
      const short* wp = wtb + (long long)(nbase + arow) * K9 + c * 64 + kq4 * 16;
      *(bf16x8*)&Bs[arow][kq4 * 16] = *(const bf16x8*)wp;
      *(bf16x8*)&Bs[arow][kq4 * 16 + 8] = *(const bf16x8*)(wp + 8);
    }
    __syncthreads();
    #pragma unroll
    for (int kk = 0; kk < 2; kk++) {
      bf16x8 a0 = *(const bf16x8*)&As[wr * 32 + (lane & 15)][kk * 32 + (lane >> 4) * 8];
      bf16x8 a1 = *(const bf16x8*)&As[wr * 32 + 16 + (lane & 15)][kk * 32 + (lane >> 4) * 8];
      bf16x8 b0 = *(const bf16x8*)&Bs[wc * 32 + (lane & 15)][kk * 32 + (lane >> 4) * 8];
      bf16x8 b1 = *(const bf16x8*)&Bs[wc * 32 + 16 + (lane & 15)][kk * 32 + (lane >> 4) * 8];
      acc[0][0] = __builtin_amdgcn_mfma_f32_16x16x32_bf16(a0, b0, acc[0][0], 0, 0, 0);
      acc[0][1] = __builtin_amdgcn_mfma_f32_16x16x32_bf16(a0, b1, acc[0][1], 0, 0, 0);
      acc[1][0] = __builtin_amdgcn_mfma_f32_16x16x32_bf16(a1, b0, acc[1][0], 0, 0, 0);
      acc[1][1] = __builtin_amdgcn_mfma_f32_16x16x32_bf16(a1, b1, acc[1][1], 0, 0, 0);
    }
  }
  int col0 = nbase + wc * 32 + (lane & 15);
  int row0 = wr * 32 + ((lane >> 4) << 2);
  #pragma unroll
  for (int nf = 0; nf < 2; nf++) {
    int co = col0 + nf * 16;
    float bv = bias[co];
    #pragma unroll
    for (int mf = 0; mf < 2; mf++)
      #pragma unroll
      for (int i = 0; i < 4; i++) {
        int x = row0 + mf * 16 + i;
        long long oi = (((long long)b * pitchO + y + padO) * pitchO + (x + padO)) * DIMC + co;
        float val = acc[mf][nf][i] + bv;
        if (OF32) ((float*)outv)[oi] = val;
        else ((unsigned short*)outv)[oi] = (unsigned short)f2bf(val);
      }
  }
}

// per-query attention probs -> attnb bf16 [bq][49][8]
__global__ __launch_bounds__(64) void k_attn(const float* __restrict__ sc,
                                             const float* __restrict__ fq,
                                             const unsigned short* __restrict__ fkb,
                                             unsigned short* __restrict__ attnO) {
  int bq = blockIdx.x;
  int b = bq >> 12;
  int lane = threadIdx.x;
  float cy = sc[bq * 2 + 0], cx = sc[bq * 2 + 1];
  float py = (cy + 1.f) * 32.f - 0.5f, px = (cx + 1.f) * 32.f - 0.5f;
  float fy = floorf(py), fx = floorf(px);
  float wy = py - fy, wx = px - fx;
  int iy = (int)fy, ix = (int)fx;
  __shared__ __align__(16) float qv[192];
  {
    const float* base = fq + (((long long)b * P1 + iy + 1) * P1 + (ix + 1)) * DIMC;
    #pragma unroll
    for (int u = 0; u < 3; u++) {
      int c = lane * 3 + u;
      float v00 = base[c], v01 = base[DIMC + c];
      float v10 = base[P1 * DIMC + c], v11 = base[P1 * DIMC + DIMC + c];
      qv[c] = (1.f - wy) * ((1.f - wx) * v00 + wx * v01) +
              wy * ((1.f - wx) * v10 + wx * v11);
    }
  }
  __syncthreads();
  int icy = min(max((int)floorf(py + 0.5f), 0), 63);
  int icx = min(max((int)floorf(px + 0.5f), 0), 63);
  float l[8];
  #pragma unroll
  for (int h = 0; h < 8; h++) l[h] = -1e30f;
  if (lane < 49) {
    int dy = lane / 7 - 3, dx = lane % 7 - 3;
    const unsigned short* kb =
        fkb + (((long long)b * P3 + icy + dy + 3) * P3 + (icx + dx + 3)) * DIMC;
    #pragma unroll
    for (int h = 0; h < 8; h++) l[h] = 0.f;
    #pragma unroll
    for (int c8 = 0; c8 < 24; c8++) {
      u16x8 k8 = *(const u16x8*)(kb + c8 * 8);
      float4 qa = *(const float4*)&qv[c8 * 8];
      float4 qb = *(const float4*)&qv[c8 * 8 + 4];
      l[c8 / 3] += qa.x * bf2f(k8[0]) + qa.y * bf2f(k8[1]) + qa.z * bf2f(k8[2]) +
                   qa.w * bf2f(k8[3]) + qb.x * bf2f(k8[4]) + qb.y * bf2f(k8[5]) +
                   qb.z * bf2f(k8[6]) + qb.w * bf2f(k8[7]);
    }
    const float s = 0.20412414523193154f;  // 1/sqrt(24)
    #pragma unroll
    for (int h = 0; h < 8; h++) l[h] *= s;
  }
  bf16x8 a8;
  #pragma unroll
  for (int h = 0; h < 8; h++) {
    float mx = l[h];
    #pragma unroll
    for (int s = 1; s < 64; s <<= 1) mx = fmaxf(mx, __shfl_xor(mx, s));
    float e = (lane < 49) ? expf(l[h] - mx) : 0.f;
    float sm = e;
    #pragma unroll
    for (int s = 1; s < 64; s <<= 1) sm += __shfl_xor(sm, s);
    a8[h] = f2bf(e / sm);
  }
  if (lane < 49) {
    *(bf16x8*)(attnO + ((long long)bq * 49 + lane) * 8) = a8;
  }
}

// fused gather+attn+GEMM, K-split 2, N-split 2: partial[kq][8192][256] f32
__global__ __launch_bounds__(256) void k_l0m(const float* __restrict__ sc,
                                             const unsigned short* __restrict__ fvb,
                                             const unsigned short* __restrict__ attn,
                                             const short* __restrict__ w0t,
                                             float* __restrict__ part) {
  int L = blockIdx.x + (blockIdx.y << 2);   // [0,512)
  int xcd = L & 7, slot = L >> 3;
  int kq = xcd >> 2, nh = (xcd >> 1) & 1;
  int mb = ((xcd & 1) << 6) | slot;
  int qbase = mb * 64;
  int b = mb >> 6;
  int t = threadIdx.x;
  int lane = t & 63, w = t >> 6, wr = w >> 1, wc = w & 1;
  __shared__ __align__(16) short As[64][72];
  __shared__ __align__(16) short Bs[128][72];
  int arow = t >> 2, kq4 = t & 3;
  int q = qbase + arow;
  float cy = sc[q * 2 + 0], cx = sc[q * 2 + 1];
  float py = (cy + 1.f) * 32.f - 0.5f, px = (cx + 1.f) * 32.f - 0.5f;
  int icy = min(max((int)floorf(py + 0.5f), 0), 63);
  int icx = min(max((int)floorf(px + 0.5f), 0), 63);
  const unsigned short* fvp = fvb + (((long long)b * P3 + icy + 3) * P3 + (icx + 3)) * DIMC;
  const unsigned short* ap = attn + (long long)q * 392;
  int ch0 = kq4 * 16;
  int nbase = nh * 128;
  int nB = t >> 1, hB = t & 1;
  f32x4 acc[2][4];
  #pragma unroll
  for (int i = 0; i < 2; i++)
    #pragma unroll
    for (int j = 0; j < 4; j++) acc[i][j] = (f32x4){0.f, 0.f, 0.f, 0.f};
  int c0 = kq * 74, cnt = kq ? 73 : 74;
  for (int ci = 0; ci < cnt; ci++) {
    int cc = c0 + ci;
    int r = cc / 3, sub = cc - r * 3;
    int dy2 = r / 7 - 3, dx2 = r % 7 - 3;
    long long tap = ((long long)dy2 * P3 + dx2) * DIMC;
    __syncthreads();
    {
      const unsigned short* src = fvp + tap + sub * 64 + ch0;
      u16x8 r0 = *(const u16x8*)src;
      u16x8 r1 = *(const u16x8*)(src + 8);
      int cA = sub * 64 + ch0;
      float a0 = bf2f(ap[r * 8 + cA / 24]);
      float a1 = bf2f(ap[r * 8 + (cA + 8) / 24]);
      bf16x8 pk0, pk1;
      #pragma unroll
      for (int e = 0; e < 8; e++) pk0[e] = f2bf(bf2f(r0[e]) * a0);
      #pragma unroll
      for (int e = 0; e < 8; e++) pk1[e] = f2bf(bf2f(r1[e]) * a1);
      *(bf16x8*)&As[arow][ch0] = pk0;
      *(bf16x8*)&As[arow][ch0 + 8] = pk1;
      const short* wp = w0t + (long long)(nbase + nB) * 9408 + cc * 64 + hB * 32;
      *(bf16x8*)&Bs[nB][hB * 32] = *(const bf16x8*)wp;
      *(bf16x8*)&Bs[nB][hB * 32 + 8] = *(const bf16x8*)(wp + 8);
      *(bf16x8*)&Bs[nB][hB * 32 + 16] = *(const bf16x8*)(wp + 16);
      *(bf16x8*)&Bs[nB][hB * 32 + 24] = *(const bf16x8*)(wp + 24);
    }
    __syncthreads();
    #pragma unroll
    for (int kk = 0; kk < 2; kk++) {
      bf16x8 av[2], bv[4];
      #pragma unroll
      for (int mf = 0; mf < 2; mf++)
        av[mf] = *(const bf16x8*)&As[wr * 32 + mf * 16 + (lane & 15)][kk * 32 + (lane >> 4) * 8];
      #pragma unroll
      for (int nf = 0; nf < 4; nf++)
        bv[nf] = *(const bf16x8*)&Bs[wc * 64 + nf * 16 + (lane & 15)][kk * 32 + (lane >> 4) * 8];
      #pragma unroll
      for (int mf = 0; mf < 2; mf++)
        #pragma unroll
        for (int nf = 0; nf < 4; nf++)
          acc[mf][nf] = __builtin_amdgcn_mfma_f32_16x16x32_bf16(av[mf], bv[nf], acc[mf][nf], 0, 0, 0);
    }
  }
  float* p = part + (long long)kq * 2097152;
  int row0 = wr * 32 + ((lane >> 4) << 2);
  int col0 = nbase + wc * 64 + (lane & 15);
  #pragma unroll
  for (int mf = 0; mf < 2; mf++)
    #pragma unroll
    for (int nf = 0; nf < 4; nf++)
      #pragma unroll
      for (int i = 0; i < 4; i++)
        p[(long long)(qbase + row0 + mf * 16 + i) * 256 + col0 + nf * 16] = acc[mf][nf][i];
}

// sum 2 partials + tail + relu -> h bf16
__global__ __launch_bounds__(256) void k_l0red(const float* __restrict__ part,
                                               const float* __restrict__ cell,
                                               const float* __restrict__ w0,
                                               const float* __restrict__ b0,
                                               unsigned short* __restrict__ h) {
  int gid = blockIdx.x * 256 + threadIdx.x;
  int q = gid >> 6, n0 = (gid & 63) << 2;
  int b = q >> 12;
  float rc0 = cell[b * 2 + 0] * 64.f, rc1 = cell[b * 2 + 1] * 64.f;
  float4 s0 = ((const float4*)part)[gid];
  float4 s1 = ((const float4*)(part + 2097152))[gid];
  unsigned short o[4];
  #pragma unroll
  for (int j = 0; j < 4; j++) {
    int n = n0 + j;
    float tailv = rc0 * w0[9408LL * 256 + n] + rc1 * w0[9409LL * 256 + n] + b0[n];
    float v = ((const float*)&s0)[j] + ((const float*)&s1)[j] + tailv;
    o[j] = (unsigned short)f2bf(fmaxf(v, 0.f));
  }
  *(uint2*)(h + (long long)gid * 4) = *(uint2*)o;
}

// fc: h_out = relu(h_in[8192,256]bf16 @ wt[n][k]bf16 + bias), out bf16
__global__ __launch_bounds__(256) void k_fcm(const unsigned short* __restrict__ hin,
                                             const short* __restrict__ wt,
                                             const float* __restrict__ bias,
                                             unsigned short* __restrict__ hout) {
  int nb = blockIdx.x, mb = blockIdx.y;
  int qbase = mb * 64, nbase = nb * 64;
  int t = threadIdx.x;
  int lane = t & 63, w = t >> 6, wr = w >> 1, wc = w & 1;
  __shared__ __align__(16) short As[64][264];
  __shared__ __align__(16) short Bs[64][264];
  int row = t >> 2, seg = t & 3;
  {
    const unsigned short* hp = hin + (long long)(qbase + row) * 256 + seg * 64;
    const short* wp = wt + (long long)(nbase + row) * 256 + seg * 64;
    #pragma unroll
    for (int j = 0; j < 8; j++) {
      *(bf16x8*)&As[row][seg * 64 + j * 8] = *(const bf16x8*)(hp + j * 8);
      *(bf16x8*)&Bs[row][seg * 64 + j * 8] = *(const bf16x8*)(wp + j * 8);
    }
  }
  __syncthreads();
  f32x4 acc[2][2];
  #pragma unroll
  for (int i = 0; i < 2; i++)
    #pragma unroll
    for (int j = 0; j < 2; j++) acc[i][j] = (f32x4){0.f, 0.f, 0.f, 0.f};
  #pragma unroll
  for (int kk = 0; kk < 8; kk++) {
    bf16x8 a0 = *(const bf16x8*)&As[wr * 32 + (lane & 15)][kk * 32 + (lane >> 4) * 8];
    bf16x8 a1 = *(const bf16x8*)&As[wr * 32 + 16 + (lane & 15)][kk * 32 + (lane >> 4) * 8];
    bf16x8 b0 = *(const bf16x8*)&Bs[wc * 32 + (lane & 15)][kk * 32 + (lane >> 4) * 8];
    bf16x8 b1 = *(const bf16x8*)&Bs[wc * 32 + 16 + (lane & 15)][kk * 32 + (lane >> 4) * 8];
    acc[0][0] = __builtin_amdgcn_mfma_f32_16x16x32_bf16(a0, b0, acc[0][0], 0, 0, 0);
    acc[0][1] = __builtin_amdgcn_mfma_f32_16x16x32_bf16(a0, b1, acc[0][1], 0, 0, 0);
    acc[1][0] = __builtin_amdgcn_mfma_f32_16x16x32_bf16(a1, b0, acc[1][0], 0, 0, 0);
    acc[1][1] = __builtin_amdgcn_mfma_f32_16x16x32_bf16(a1, b1, acc[1][1], 0, 0, 0);
  }
  int row0 = wr * 32 + ((lane >> 4) << 2);
  int col0 = nbase + wc * 32 + (lane & 15);
  #pragma unroll
  for (int nf = 0; nf < 2; nf++) {
    int n = col0 + nf * 16;
    float bv = bias[n];
    #pragma unroll
    for (int mf = 0; mf < 2; mf++)
      #pragma unroll
      for (int i = 0; i < 4; i++)
        hout[(long long)(qbase + row0 + mf * 16 + i) * 256 + n] =
            (unsigned short)f2bf(fmaxf(acc[mf][nf][i] + bv, 0.f));
  }
}

// out = h3(bf16) @ m4w + m4b + bilinear(inp, border=True)
__global__ __launch_bounds__(64) void k_final(const unsigned short* __restrict__ h3,
                                              const float* __restrict__ w4,
                                              const float* __restrict__ b4,
                                              const float* __restrict__ sc,
                                              const float* __restrict__ inp,
                                              float* __restrict__ out) {
  int bq = blockIdx.x;
  int b = bq >> 12;
  int lane = threadIdx.x;
  float p0 = 0.f, p1 = 0.f, p2 = 0.f;
  const unsigned short* hr = h3 + (long long)bq * 256;
  #pragma unroll
  for (int u = 0; u < 4; u++) {
    int c = lane + u * 64;
    float hv = bf2f(hr[c]);
    p0 += hv * w4[c * 3 + 0];
    p1 += hv * w4[c * 3 + 1];
    p2 += hv * w4[c * 3 + 2];
  }
  #pragma unroll
  for (int s = 1; s < 64; s <<= 1) {
    p0 += __shfl_xor(p0, s);
    p1 += __shfl_xor(p1, s);
    p2 += __shfl_xor(p2, s);
  }
  if (lane == 0) {
    float cy = sc[bq * 2 + 0], cx = sc[bq * 2 + 1];
    float py = (cy + 1.f) * 32.f - 0.5f, px = (cx + 1.f) * 32.f - 0.5f;
    float fy = floorf(py), fx = floorf(px);
    float wy = py - fy, wx = px - fx;
    int y0 = (int)fy, x0 = (int)fx;
    int yc0 = min(max(y0, 0), 63), yc1 = min(max(y0 + 1, 0), 63);
    int xc0 = min(max(x0, 0), 63), xc1 = min(max(x0 + 1, 0), 63);
    float o[3] = {p0 + b4[0], p1 + b4[1], p2 + b4[2]};
    #pragma unroll
    for (int j = 0; j < 3; j++) {
      const float* im = inp + ((long long)b * 3 + j) * 4096;
      float s00 = im[yc0 * 64 + xc0], s01 = im[yc0 * 64 + xc1];
      float s10 = im[yc1 * 64 + xc0], s11 = im[yc1 * 64 + xc1];
      o[j] += (1.f - wy) * ((1.f - wx) * s00 + wx * s01) +
              wy * ((1.f - wx) * s10 + wx * s11);
      out[(long long)bq * 3 + j] = o[j];
    }
  }
}

extern "C" void kernel_launch(void* const* d_in, const int* in_sizes, int n_in,
                              void* d_out, int out_size, void* d_ws, size_t ws_size,
                              hipStream_t stream) {
  const float* inp = (const float*)d_in[0];
  const float* sc = (const float*)d_in[1];
  const float* cell = (const float*)d_in[2];
  const float* enc_w = (const float*)d_in[3];
  const float* enc_b = (const float*)d_in[4];
  const float* ch_w = (const float*)d_in[5];
  const float* ch_b = (const float*)d_in[6];
  const float* q_w = (const float*)d_in[7];
  const float* q_b = (const float*)d_in[8];
  const float* k_w = (const float*)d_in[9];
  const float* k_b = (const float*)d_in[10];
  const float* v_w = (const float*)d_in[11];
  const float* v_b = (const float*)d_in[12];
  const float* m0w = (const float*)d_in[13];
  const float* m0b = (const float*)d_in[14];
  const float* m1w = (const float*)d_in[15];
  const float* m1b = (const float*)d_in[16];
  const float* m2w = (const float*)d_in[17];
  const float* m2b = (const float*)d_in[18];
  const float* m3w = (const float*)d_in[19];
  const float* m3b = (const float*)d_in[20];
  const float* m4w = (const float*)d_in[21];
  const float* m4b = (const float*)d_in[22];
  float* ws = (float*)d_ws;
  unsigned short* f1p = (unsigned short*)(ws + F_F1);
  unsigned short* featp = (unsigned short*)(ws + F_FEAT);
  float* featqp = ws + F_FQ;
  float* part = ws + F_PART;
  unsigned short* fkb = (unsigned short*)(ws + F_FKB);
  unsigned short* fvb = (unsigned short*)(ws + F_FVB);
  unsigned short* attnb = (unsigned short*)(ws + F_ATTN);
  short* w0t = (short*)(ws + F_W0T);
  short* wtb_ch = (short*)(ws + F_WTCH);
  short* wtb_q = (short*)(ws + F_WTQ);
  short* wtb_k = (short*)(ws + F_WTK);
  short* wtb_v = (short*)(ws + F_WTV);
  short* wfc1 = (short*)(ws + F_WFC1);
  short* wfc2 = (short*)(ws + F_WFC2);
  short* wfc3 = (short*)(ws + F_WFC3);
  unsigned short* h_a = (unsigned short*)(ws + F_HA);
  unsigned short* h_b = (unsigned short*)(ws + F_HB);
  float* outp = (float*)d_out;

  k_zero<<<1024, 256, 0, stream>>>((float4*)ws, (int)(ZA_END / 4));
  k_zero<<<1024, 256, 0, stream>>>((float4*)(ws + F_FKB), (int)(1881600 / 4));
  k_w0t<<<dim3(147, 4), 256, 0, stream>>>(m0w, w0t);
  k_wtb<<<(192 * 64 * 9 + 255) / 256, 256, 0, stream>>>(ch_w, wtb_ch, 64, 192);
  k_wtb<<<(192 * 192 * 9 + 255) / 256, 256, 0, stream>>>(q_w, wtb_q, 192, 192);
  k_wtb<<<(192 * 192 * 9 + 255) / 256, 256, 0, stream>>>(k_w, wtb_k, 192, 192);
  k_wtb<<<(192 * 192 * 9 + 255) / 256, 256, 0, stream>>>(v_w, wtb_v, 192, 192);
  k_wfc<<<256, 256, 0, stream>>>(m1w, wfc1);
  k_wfc<<<256, 256, 0, stream>>>(m2w, wfc2);
  k_wfc<<<256, 256, 0, stream>>>(m3w, wfc3);
  k_conv1<<<(BB * 64 * 64 * ENC) / 256, 256, 0, stream>>>(inp, enc_w, enc_b, f1p);
  k_conv3x3m<64, false><<<dim3(3, BB * 64), 256, 0, stream>>>(f1p, wtb_ch, ch_b, featp, P1, 1);
  k_conv3x3m<192, true><<<dim3(3, BB * 64), 256, 0, stream>>>(featp, wtb_q, q_b, featqp, P1, 1);
  k_conv3x3m<192, false><<<dim3(3, BB * 64), 256, 0, stream>>>(featp, wtb_k, k_b, fkb, P3, 3);
  k_conv3x3m<192, false><<<dim3(3, BB * 64), 256, 0, stream>>>(featp, wtb_v, v_b, fvb, P3, 3);
  k_attn<<<BB * QQ, 64, 0, stream>>>(sc, featqp, fkb, attnb);
  k_l0m<<<dim3(4, 128), 256, 0, stream>>>(sc, fvb, attnb, w0t, part);
  k_l0red<<<2048, 256, 0, stream>>>(part, cell, m0w, m0b, h_a);
  k_fcm<<<dim3(4, 128), 256, 0, stream>>>(h_a, wfc1, m1b, h_b);
  k_fcm<<<dim3(4, 128), 256, 0, stream>>>(h_b, wfc2, m2b, h_a);
  k_fcm<<<dim3(4, 128), 256, 0, stream>>>(h_a, wfc3, m3b, h_b);
  k_final<<<BB * QQ, 64, 0, stream>>>(h_b, m4w, m4b, sc, inp, outp);
}